// Round 1
// 1079.568 us; speedup vs baseline: 1.0401x; 1.0401x over previous
//
#include <hip/hip_runtime.h>

#define T_STEPS 1024
#define FDIM    2048
#define LAT     128
#define HID     256
#define MB      8             // features per block
#define NTHR    512           // 8 waves, 2 per SIMD
#define NBLK    (FDIM / MB)   // 256 blocks = 1/CU

typedef __attribute__((ext_vector_type(8))) short bf16x8;
typedef __attribute__((ext_vector_type(4))) float f32x4;

#define L2E  1.4426950408889634f   // log2(e)
#define C2E  2.8853900817779268f   // 2*log2(e)

__device__ __forceinline__ float exp2_(float x) {
#if __has_builtin(__builtin_amdgcn_exp2f)
    return __builtin_amdgcn_exp2f(x);
#else
    return __expf(0.6931471805599453f * x);
#endif
}
__device__ __forceinline__ float rcp_(float x) { return __builtin_amdgcn_rcpf(x); }
// tanh(y) = 1 - 2/(1+2^(C2E*y)): inf-safe (y->+inf: 2^big=inf, rcp=0, ->1;
// y->-inf: 2^small=0, rcp(1)=1, ->-1). 5 instr with bias folded into exp2 domain.

__device__ __forceinline__ unsigned short f2bu(float x) {   // fp32->bf16 RNE bits
    unsigned u = __float_as_uint(x);
    u += 0x7fffu + ((u >> 16) & 1u);
    return (unsigned short)(u >> 16);
}
__device__ __forceinline__ short f2b(float x) { return (short)f2bu(x); }

// packed fp32->bf16 RNE in ONE instruction (replaces ~10-instr manual pack).
// v_cvt_pk_bf16_f32: D[15:0]=bf16(S0), D[31:16]=bf16(S1), round-nearest-even.
__device__ __forceinline__ unsigned pk2(float a, float b) {
    unsigned r;
    asm("v_cvt_pk_bf16_f32 %0, %1, %2" : "=v"(r) : "v"(a), "v"(b));
    return r;
}

// LDS-only barrier. __syncthreads() emits s_waitcnt vmcnt(0) lgkmcnt(0) before
// s_barrier, which drains the in-flight x/mask prefetch loads every step
// (~L3/HBM latency, cross-XCD lines -> per-XCD L2 miss). All cross-wave data
// here moves through LDS, so lgkmcnt(0) alone gives the required visibility;
// global loads are lane-private and may stay in flight across the barrier.
__device__ __forceinline__ void bar_lds() {
    asm volatile("s_waitcnt lgkmcnt(0)" ::: "memory");
    __builtin_amdgcn_s_barrier();
    asm volatile("" ::: "memory");   // fence: no LDS reads hoisted above barrier
}

// pick owned row-pair from a C-fragment: hf=0 -> (v0,v1), hf=1 -> (v2,v3)
__device__ __forceinline__ float2 pick2(f32x4 v, int hf) {
    float a = hf ? v[2] : v[0];
    float b = hf ? v[3] : v[1];
    return make_float2(a, b);
}

// Activation^T LDS layout (B-operand): element (k, m) at short-offset
//   (k>>3)*64 + m*8 + (k&7)   [m in 0..7]
// B-frag read for lane (col,qd): 16B contiguous at (kb*4+qd)*64 + (col&7)*8;
// cols 8..15 duplicate cols 0..7 (same-address broadcast).

__global__ __launch_bounds__(NTHR, 2)
void odernn_kernel(const float* __restrict__ times,
                   const float* __restrict__ vals,
                   const float* __restrict__ mask,
                   const float* __restrict__ W1,  const float* __restrict__ b1,
                   const float* __restrict__ W2,  const float* __restrict__ b2,
                   const float* __restrict__ W_ih, const float* __restrict__ b_ih,
                   const float* __restrict__ Whh, const float* __restrict__ b_hh,
                   float* __restrict__ out)
{
    __shared__ float dts_s[T_STEPS];   // 4 KB
    __shared__ short hTpre[16 * 64];   // 2 KB  bf16 h^T (post-GRU)
    __shared__ short hTpost[16 * 64];  // 2 KB  bf16 h^T (post-ODE)
    __shared__ short uT[32 * 64];      // 4 KB  bf16 u^T

    const int tid = threadIdx.x;
    const int w   = tid >> 6;          // wave 0..7
    const int ln  = tid & 63;
    const int col = ln & 15;           // C/D col = feature (8..15 duplicate 0..7)
    const int qd  = ln >> 4;           // quad; C/D row = qd*4 + reg
    const int m8  = ln & 7;            // feature index
    const int hf  = (ln >> 3) & 1;     // row-half ownership: rows qd*4 + hf*2 + {0,1}
    const int fbase = blockIdx.x * MB;
    const int rbase = qd * 64 + m8 * 8;     // B-frag read offset (shorts)

    // ---------- prologue ----------
    for (int e = tid; e < T_STEPS; e += NTHR)
        dts_s[e] = (e == 0) ? 0.0f : (times[T_STEPS - e] - times[T_STEPS - 1 - e]);
    for (int e = tid; e < 16 * 64; e += NTHR) { hTpre[e] = 0; hTpost[e] = 0; }

    // A-operand weight fragment: lane holds W[tb+col][kb*32 + qd*8 + j]
    auto loadW = [&](const float* __restrict__ W, int K, int tb, int kb) -> bf16x8 {
        const float* p = W + (size_t)(tb + col) * K + kb * 32 + qd * 8;
        const float4 a = *(const float4*)p;
        const float4 b = *(const float4*)(p + 4);
        bf16x8 r;
        r[0] = f2b(a.x); r[1] = f2b(a.y); r[2] = f2b(a.z); r[3] = f2b(a.w);
        r[4] = f2b(b.x); r[5] = f2b(b.y); r[6] = f2b(b.z); r[7] = f2b(b.w);
        return r;
    };

    // per-wave tiles (112 weight regs/lane, AGPR-resident):
    // p1: u-tiles {2w, 2w+1}; p2: ode-tile w; p3: gate tiles {w, 8+w, 16+w}
    bf16x8 w1a[2][4];
    #pragma unroll
    for (int i = 0; i < 2; ++i)
        #pragma unroll
        for (int kb = 0; kb < 4; ++kb) w1a[i][kb] = loadW(W1, LAT, (2 * w + i) * 16, kb);
    bf16x8 w2a[8];
    #pragma unroll
    for (int kb = 0; kb < 8; ++kb) w2a[kb] = loadW(W2, HID, w * 16, kb);
    bf16x8 wha[3][4];
    #pragma unroll
    for (int g = 0; g < 3; ++g)
        #pragma unroll
        for (int kb = 0; kb < 4; ++kb)
            wha[g][kb] = loadW(Whh, LAT, g * 128 + w * 16, kb);

    // per-lane constants for OWNED rows c = w*16 + qd*4 + hf*2 + j,
    // pre-scaled into the exp2 domain so each activation is minimal-instr:
    //  p1 tanh:  arg2 = fmaf(a1, C2E, cb1)                  (cb1 = C2E*b1)
    //  r/z sig:  arg2 = fmaf(a3, -L2E, fmaf(x, wS, bS))     (wS=-L2E*wih, bS=-L2E*(bih+bhh))
    //  n  tanh:  arg2 = fmaf(r, fmaf(a3n, C2E, bhnC), fmaf(x, wnC, bnC))
    float cb1L[2][2], b2L[2];
    float wrS[2], brS[2], wzS[2], bzS[2], wnC[2], bnC[2], bhnC[2];
    #pragma unroll
    for (int i = 0; i < 2; ++i)
        #pragma unroll
        for (int j = 0; j < 2; ++j)
            cb1L[i][j] = C2E * b1[(2 * w + i) * 16 + qd * 4 + hf * 2 + j];
    #pragma unroll
    for (int j = 0; j < 2; ++j) {
        const int c = w * 16 + qd * 4 + hf * 2 + j;
        b2L[j]  = b2[c];
        wrS[j]  = -L2E * W_ih[c];
        brS[j]  = -L2E * (b_ih[c] + b_hh[c]);
        wzS[j]  = -L2E * W_ih[128 + c];
        bzS[j]  = -L2E * (b_ih[128 + c] + b_hh[128 + c]);
        wnC[j]  =  C2E * W_ih[256 + c];
        bnC[j]  =  C2E * b_ih[256 + c];
        bhnC[j] =  C2E * b_hh[256 + c];
    }
    float hreg[2] = {0.f, 0.f};   // fp32 master h: rows w*16+qd*4+hf*2+{0,1}, feature m8
    const int myAddr = (w * 2 + (qd >> 1)) * 64 + m8 * 8 + (qd & 1) * 4 + hf * 2;

    // decrementing observation pointers (row T-1-t, own feature)
    const float* vp = vals + (size_t)(T_STEPS - 1) * FDIM + fbase + m8;
    const float* mp = mask + (size_t)(T_STEPS - 1) * FDIM + fbase + m8;
    // preload step 0's observation; in-loop we prefetch one FULL step ahead so
    // the ~700-900 cy cross-XCD load latency hides under an entire step.
    float xc = *vp;
    float mc = *mp;

    __syncthreads();

    // Branch-free loop: dt==0 gives h' = fmaf(0, ode, h) == h bit-exactly, so
    // the reference's where(dt>0) needs no control flow (ties ~never anyway).
    for (int t = 0; t < T_STEPS; ++t) {
        const float dt = dts_s[t];

        // issue next step's observation loads NOW; they stay in flight across
        // the (lgkmcnt-only) barriers and are first consumed next iteration.
        float xn = 0.f, mn = 0.f;
        if (t + 1 < T_STEPS) {
            vp -= FDIM; mp -= FDIM;
            xn = *vp;
            mn = *mp;
        }

        // ---- p1: u^T = tanh(W1 h^T + b1), 2 tiles ----
        f32x4 a1[2] = {{0,0,0,0},{0,0,0,0}};
        #pragma unroll
        for (int kb = 0; kb < 4; ++kb) {
            const bf16x8 bf = *(const bf16x8*)(hTpre + kb * 256 + rbase);
            #pragma unroll
            for (int i = 0; i < 2; ++i)
                a1[i] = __builtin_amdgcn_mfma_f32_16x16x32_bf16(w1a[i][kb], bf, a1[i], 0, 0, 0);
        }
        #pragma unroll
        for (int i = 0; i < 2; ++i) {
            const float2 p = pick2(a1[i], hf);
            const float v0 = fmaf(-2.f, rcp_(1.f + exp2_(fmaf(p.x, C2E, cb1L[i][0]))), 1.f);
            const float v1 = fmaf(-2.f, rcp_(1.f + exp2_(fmaf(p.y, C2E, cb1L[i][1]))), 1.f);
            const int addr = ((2 * w + i) * 2 + (qd >> 1)) * 64 + m8 * 8 + (qd & 1) * 4 + hf * 2;
            *(unsigned*)(uT + addr) = pk2(v0, v1);
        }
        bar_lds();

        // ---- p2: ode^T = W2 u^T + b2 ; h += dt*ode. Dual accumulators to
        // halve the serial MFMA dependency chain (8 -> 4+4). ----
        f32x4 a2a = {0,0,0,0}, a2b = {0,0,0,0};
        #pragma unroll
        for (int kb = 0; kb < 4; ++kb) {
            const bf16x8 bfa = *(const bf16x8*)(uT + kb * 256 + rbase);
            const bf16x8 bfb = *(const bf16x8*)(uT + (kb + 4) * 256 + rbase);
            a2a = __builtin_amdgcn_mfma_f32_16x16x32_bf16(w2a[kb],     bfa, a2a, 0, 0, 0);
            a2b = __builtin_amdgcn_mfma_f32_16x16x32_bf16(w2a[kb + 4], bfb, a2b, 0, 0, 0);
        }
        {
            const f32x4 a2 = a2a + a2b;
            const float2 p = pick2(a2, hf);
            hreg[0] = fmaf(dt, p.x + b2L[0], hreg[0]);
            hreg[1] = fmaf(dt, p.y + b2L[1], hreg[1]);
            *(unsigned*)(hTpost + myAddr) = pk2(hreg[0], hreg[1]);
        }
        bar_lds();

        // ---- p3: gh^T = Whh h'^T (+ biases folded), GRU fully in-register ----
        f32x4 a3[3] = {{0,0,0,0},{0,0,0,0},{0,0,0,0}};
        #pragma unroll
        for (int kb = 0; kb < 4; ++kb) {
            const bf16x8 bf = *(const bf16x8*)(hTpost + kb * 256 + rbase);
            #pragma unroll
            for (int g = 0; g < 3; ++g)
                a3[g] = __builtin_amdgcn_mfma_f32_16x16x32_bf16(wha[g][kb], bf, a3[g], 0, 0, 0);
        }
        {
            const float2 gR = pick2(a3[0], hf);
            const float2 gZ = pick2(a3[1], hf);
            const float2 gN = pick2(a3[2], hf);
            const float gRv[2] = {gR.x, gR.y}, gZv[2] = {gZ.x, gZ.y}, gNv[2] = {gN.x, gN.y};
            #pragma unroll
            for (int j = 0; j < 2; ++j) {
                const float sr = rcp_(1.f + exp2_(fmaf(gRv[j], -L2E, fmaf(xc, wrS[j], brS[j]))));
                const float sz = rcp_(1.f + exp2_(fmaf(gZv[j], -L2E, fmaf(xc, wzS[j], bzS[j]))));
                const float yn = fmaf(sr, fmaf(gNv[j], C2E, bhnC[j]), fmaf(xc, wnC[j], bnC[j]));
                const float nn = fmaf(-2.f, rcp_(1.f + exp2_(yn)), 1.f);
                const float hv = hreg[j];
                const float hc = fmaf(sz, hv - nn, nn);          // (1-z)n + z*h
                hreg[j] = fmaf(mc, hc - hv, hv);                 // mask blend
            }
            *(unsigned*)(hTpre + myAddr) = pk2(hreg[0], hreg[1]);
        }
        bar_lds();

        xc = xn; mc = mn;   // rotate prefetched observation into place
    }

    {
        float2 o = make_float2(hreg[0], hreg[1]);
        *(float2*)(out + (size_t)(fbase + m8) * LAT + w * 16 + qd * 4 + hf * 2) = o;
    }
}

extern "C" void kernel_launch(void* const* d_in, const int* in_sizes, int n_in,
                              void* d_out, int out_size, void* d_ws, size_t ws_size,
                              hipStream_t stream) {
    const float* times = (const float*)d_in[0];
    const float* vals  = (const float*)d_in[1];
    const float* mask  = (const float*)d_in[2];
    const float* W1    = (const float*)d_in[3];
    const float* b1    = (const float*)d_in[4];
    const float* W2    = (const float*)d_in[5];
    const float* b2    = (const float*)d_in[6];
    const float* W_ih  = (const float*)d_in[7];
    const float* b_ih  = (const float*)d_in[8];
    const float* Whh   = (const float*)d_in[9];
    const float* b_hh  = (const float*)d_in[10];
    float* out = (float*)d_out;

    odernn_kernel<<<NBLK, NTHR, 0, stream>>>(times, vals, mask,
                                             W1, b1, W2, b2,
                                             W_ih, b_ih, Whh, b_hh, out);
}